// Round 4
// baseline (494.534 us; speedup 1.0000x reference)
//
#include <hip/hip_runtime.h>

// BiLSTM: B=256, T=512, N=128, H=128. fp32 in/out, bf16 MFMA internally.
//
// Round-4 architecture: split x@W off the serial path.
//   kernel 0 prep_frags: repack [W;U] into bf16 MFMA B-fragments (unchanged).
//   kernel 1 zx_gemm:    zx[dir][token][4H] = x@W + b, fp32, all 256 CUs,
//                        memory-bound (~536 MB write).
//   kernel 2 bilstm_rec_lite: recurrence with K=128 (U only): wu = 64 VGPRs
//                        (vs 128), 4-deep MFMA chain (vs 8), 4 ds_read (vs 8),
//                        h-only LDS tile, acc init = streamed zx (2-deep
//                        prefetch). 128 blocks, rows at tile rows {0,4,8,12}.
// If ws_size < 513 MB, falls back to the round-3 fused kernel (identical).
//
// ws layout:
//   [0, 512KB):        WU bf16 B-fragments [dir][gate][kc(8)][tile][lane][8]
//                      kc<4 -> W rows kc*32.., kc>=4 -> U rows (kc-4)*32..
//   [512KB, +512MB):   zx fp32 [dir][token=b*512+t][512]   (split path only)

typedef short s16x8 __attribute__((ext_vector_type(8)));
typedef float f32x4 __attribute__((ext_vector_type(4)));

#define NT 512
#define LDSROW 264   // fused-path tile stride (bf16): 132 dw, 16B-aligned

#define LDS_BARRIER() asm volatile("s_waitcnt lgkmcnt(0)\n\ts_barrier" ::: "memory")

__device__ __forceinline__ unsigned short f2bf(float f) {
  unsigned int u = __float_as_uint(f);
  u += 0x7fffu + ((u >> 16) & 1u);   // RNE
  return (unsigned short)(u >> 16);
}
__device__ __forceinline__ unsigned int packbf2(float a, float b) {
  return (unsigned int)f2bf(a) | ((unsigned int)f2bf(b) << 16);
}
__device__ __forceinline__ float sigm(float x) {
  return __builtin_amdgcn_rcpf(1.f + __expf(-x));
}
__device__ __forceinline__ float tanh_(float x) {
  float xc = fminf(fmaxf(x, -12.f), 12.f);
  return 1.f - 2.f * __builtin_amdgcn_rcpf(1.f + __expf(2.f * xc));
}

// ---------------------------------------------------------------- kernel 0
// Repack [W;U] (fp32 [128][512] each) into bf16 B-fragment order, K=256.
// B-frag (16x16x32): lane holds B[k = (lane>>4)*8 + j][n = lane&15].
__global__ void prep_frags(const float* __restrict__ Wf, const float* __restrict__ Uf,
                           const float* __restrict__ Wb, const float* __restrict__ Ub,
                           unsigned short* __restrict__ frag) {
  int idx = blockIdx.x * 256 + threadIdx.x;          // 0 .. 2^18-1
  int j    = idx & 7;
  int lane = (idx >> 3) & 63;
  int tile = (idx >> 9) & 7;
  int kc   = (idx >> 12) & 7;
  int gate = (idx >> 15) & 3;
  int dir  = (idx >> 17) & 1;
  const float* M = (kc < 4) ? (dir ? Wb : Wf) : (dir ? Ub : Uf);
  int k   = (kc & 3) * 32 + (lane >> 4) * 8 + j;
  int col = gate * 128 + tile * 16 + (lane & 15);
  frag[idx] = f2bf(M[k * 512 + col]);
}

// ---------------------------------------------------------------- kernel 1
// zx = x @ W_dir + b_dir. Grid: 4096 = 2 dirs x 2048 tiles of 64 tokens.
// 8 waves; wave tc covers 16 cols of each of the 4 gates (same col map as rec).
__global__ __launch_bounds__(512, 2) void zx_gemm(
    const unsigned short* __restrict__ frag, const float* __restrict__ x,
    const float* __restrict__ bfw, const float* __restrict__ bbw,
    float* __restrict__ zx) {
  __shared__ unsigned short xs[64][136];   // 136 = 68 dw: rows 2-way banked

  int bid = blockIdx.x;
  int tile = bid & 2047, dir = bid >> 11;
  int tid = threadIdx.x;
  int tc = tid >> 6, lane = tid & 63, quad = lane >> 4, m = lane & 15;

  // stage x tile [64 tokens][128] -> bf16 LDS (coalesced float4 loads)
  const float* xt = x + (size_t)tile * (64 * 128);
#pragma unroll
  for (int k = 0; k < 4; k++) {
    int fi = tid + k * 512;
    int row = fi >> 5, col = (fi & 31) * 4;
    float4 v = *(const float4*)(xt + row * 128 + col);
    uint2 pk; pk.x = packbf2(v.x, v.y); pk.y = packbf2(v.z, v.w);
    *(uint2*)(&xs[row][col]) = pk;
  }

  // W fragments: gate g, kc 0..3, tile tc -> 16 frags (64 VGPR)
  s16x8 wu[4][4];
#pragma unroll
  for (int g = 0; g < 4; g++)
#pragma unroll
    for (int kc = 0; kc < 4; kc++)
      wu[g][kc] = *(const s16x8*)(frag +
          ((((size_t)(dir * 4 + g) * 8 + kc) * 8 + tc) * 64 + lane) * 8);

  const float* bias = dir ? bbw : bfw;
  float bv[4];
#pragma unroll
  for (int g = 0; g < 4; g++) bv[g] = bias[g * 128 + tc * 16 + m];

  __syncthreads();

  f32x4 acc[4][4];   // [mtile][gate]
#pragma unroll
  for (int mt = 0; mt < 4; mt++)
#pragma unroll
    for (int g = 0; g < 4; g++) {
      acc[mt][g][0] = bv[g]; acc[mt][g][1] = bv[g];
      acc[mt][g][2] = bv[g]; acc[mt][g][3] = bv[g];
    }

#pragma unroll
  for (int mt = 0; mt < 4; mt++) {
    s16x8 a[4];
#pragma unroll
    for (int kc = 0; kc < 4; kc++)
      a[kc] = *(const s16x8*)(&xs[mt * 16 + m][kc * 32 + quad * 8]);
#pragma unroll
    for (int kc = 0; kc < 4; kc++)
#pragma unroll
      for (int g = 0; g < 4; g++)
        acc[mt][g] = __builtin_amdgcn_mfma_f32_16x16x32_bf16(a[kc], wu[g][kc], acc[mt][g], 0, 0, 0);
  }

  // store: C row = quad*4+r (token within tile), col = lane&15
  float* zo = zx + (size_t)dir * ((size_t)131072 * 512) + (size_t)tile * (64 * 512);
#pragma unroll
  for (int mt = 0; mt < 4; mt++)
#pragma unroll
    for (int g = 0; g < 4; g++)
#pragma unroll
      for (int r = 0; r < 4; r++)
        zo[(size_t)(mt * 16 + quad * 4 + r) * 512 + g * 128 + tc * 16 + m] = acc[mt][g][r];
}

// ---------------------------------------------------------------- kernel 2
// Light recurrence: z = zx(t) + h@U. 128 blocks = 2 dirs x 64 batch-blocks of
// 4 rows at MFMA tile rows {0,4,8,12} (other rows permanent zero padding).
__global__ __launch_bounds__(512, 2) void bilstm_rec_lite(
    const unsigned short* __restrict__ frag, const float* __restrict__ zx,
    float* __restrict__ out) {
  __shared__ unsigned short hbuf[2][16][136];   // h cols 0..127; 2-way banks

  int bid = blockIdx.x;
  int bblk = bid & 63, dir = bid >> 6;
  int tid = threadIdx.x;
  int tc = tid >> 6, lane = tid & 63, quad = lane >> 4, m = lane & 15;
  bool mrow = ((m & 3) == 0);   // lane holds a real A-row

  // U fragments only: 16 frags -> 64 VGPRs
  s16x8 wu[4][4];   // [gate][kk], U rows kk*32..
#pragma unroll
  for (int g = 0; g < 4; g++)
#pragma unroll
    for (int kk = 0; kk < 4; kk++)
      wu[g][kk] = *(const s16x8*)(frag +
          ((((size_t)(dir * 4 + g) * 8 + 4 + kk) * 8 + tc) * 64 + lane) * 8);

  // zx base for this lane's (row = quad, col = tc*16+m); step adds t*512+g*128
  const float* zp = zx + ((size_t)dir * 131072 + (size_t)(bblk * 4 + quad) * 512) * 512
                  + tc * 16 + m;

  // zero hbuf (padding rows stay 0 forever; h(0) = 0)
  {
    unsigned int* zpp = (unsigned int*)&hbuf[0][0][0];
    for (int i = tid; i < 2 * 16 * 68; i += 512) zpp[i] = 0;
  }
  __syncthreads();

  // 2-deep zx prefetch (rotating register slots, unroll-by-2)
  float zqA[4], zqB[4];
  {
    int t0 = dir ? (NT - 1) : 0;
    int t1 = dir ? (NT - 2) : 1;
#pragma unroll
    for (int g = 0; g < 4; g++) zqA[g] = zp[(size_t)t0 * 512 + g * 128];
#pragma unroll
    for (int g = 0; g < 4; g++) zqB[g] = zp[(size_t)t1 * 512 + g * 128];
  }

  s16x8 a[4];
#pragma unroll
  for (int kk = 0; kk < 4; kk++) a[kk] = (s16x8){0, 0, 0, 0, 0, 0, 0, 0};

  float cc = 0.f;
  float* outp = out + ((size_t)(bblk * 4 + quad) * NT) * 256 + dir * 128 + tc * 16 + m;

  auto body = [&](int s, float (&zq)[4]) {
    int cb = s & 1, nb = cb ^ 1;

    // issue zx load for step s+2 (consumed 2 barriers later)
    int sn = s + 2; if (sn > NT - 1) sn = NT - 1;
    int tn = dir ? (NT - 1 - sn) : sn;
    float zn[4];
#pragma unroll
    for (int g = 0; g < 4; g++) zn[g] = zp[(size_t)tn * 512 + g * 128];

    // A-frags from h tile, exec-masked to real-row lanes (2-way banks, free)
    if (mrow) {
#pragma unroll
      for (int kk = 0; kk < 4; kk++)
        a[kk] = *(const s16x8*)(&hbuf[cb][m][kk * 32 + quad * 8]);
    }

    f32x4 acc[4];
#pragma unroll
    for (int g = 0; g < 4; g++) {
      acc[g][0] = zq[g]; acc[g][1] = zq[g]; acc[g][2] = zq[g]; acc[g][3] = zq[g];
    }
#pragma unroll
    for (int kk = 0; kk < 4; kk++)
#pragma unroll
      for (int g = 0; g < 4; g++)
        acc[g] = __builtin_amdgcn_mfma_f32_16x16x32_bf16(a[kk], wu[g][kk], acc[g], 0, 0, 0);

    // activations on the single real element: C row quad*4 (reg 0)
    float iv = sigm(acc[0][0]);
    float fv = sigm(acc[1][0]);
    float gv = tanh_(acc[2][0]);
    float ov = sigm(acc[3][0]);
    cc = fv * cc + iv * gv;
    float hv = ov * tanh_(cc);

    // LDS write gates the barrier's lgkmcnt drain
    hbuf[nb][quad * 4][tc * 16 + m] = f2bf(hv);

    // global out store stays in flight across the barrier
    outp[(size_t)s * 256] = hv;

    LDS_BARRIER();
#pragma unroll
    for (int g = 0; g < 4; g++) zq[g] = zn[g];   // rotate slot
  };

  for (int s = 0; s < NT; s += 2) {
    body(s, zqA);
    body(s + 1, zqB);
  }
}

// ---------------------------------------------------------------- kernel 2b
// Fallback (round-3 fused kernel, verbatim): used when ws can't hold zx.
__global__ __launch_bounds__(512, 2) void bilstm_rec_fused(
    const unsigned short* __restrict__ frag, const float* __restrict__ x,
    const float* __restrict__ bfw, const float* __restrict__ bbw,
    float* __restrict__ out) {
  __shared__ unsigned short xh[2][16][LDSROW];   // cols 0..127 = x_t, 128..255 = h

  int bid = blockIdx.x;
  int bblk = bid & 63, dir = bid >> 6;
  int tid = threadIdx.x;
  int tc = tid >> 6, lane = tid & 63, quad = lane >> 4, m = lane & 15;
  bool mrow = ((m & 3) == 0);

  s16x8 wu[4][8];
#pragma unroll
  for (int g = 0; g < 4; g++)
#pragma unroll
    for (int kc = 0; kc < 8; kc++)
      wu[g][kc] = *(const s16x8*)(frag +
          ((((size_t)(dir * 4 + g) * 8 + kc) * 8 + tc) * 64 + lane) * 8);

  const float* bias = dir ? bbw : bfw;
  float bv[4];
#pragma unroll
  for (int g = 0; g < 4; g++) bv[g] = bias[g * 128 + tc * 16 + m];

  int srow = tid >> 7, scol = tid & 127;
  const float* xsrc = x + ((size_t)(bblk * 4 + srow) * NT) * 128 + scol;

  {
    unsigned int* zp = (unsigned int*)&xh[0][0][0];
    for (int i = tid; i < 2 * 16 * (LDSROW / 2); i += 512) zp[i] = 0;
  }
  __syncthreads();

  {
    int t0 = dir ? (NT - 1) : 0;
    xh[0][srow * 4][scol] = f2bf(xsrc[(size_t)t0 * 128]);
  }
  float vxA = xsrc[(size_t)(dir ? (NT - 2) : 1) * 128];
  float vxB = xsrc[(size_t)(dir ? (NT - 3) : 2) * 128];
  __syncthreads();

  s16x8 a[8];
#pragma unroll
  for (int kc = 0; kc < 8; kc++) a[kc] = (s16x8){0, 0, 0, 0, 0, 0, 0, 0};

  float cc = 0.f;
  float* outp = out + ((size_t)(bblk * 4 + quad) * NT) * 256 + dir * 128 + tc * 16 + m;

  auto body = [&](int s, float& vx) {
    int cb = s & 1, nb = cb ^ 1;

    int sn = s + 3; if (sn > NT - 1) sn = NT - 1;
    int tn = dir ? (NT - 1 - sn) : sn;
    float vnew = xsrc[(size_t)tn * 128];

    if (mrow) {
#pragma unroll
      for (int kc = 0; kc < 8; kc++)
        a[kc] = *(const s16x8*)(&xh[cb][m][kc * 32 + quad * 8]);
    }

    f32x4 acc[4];
#pragma unroll
    for (int g = 0; g < 4; g++) {
      acc[g][0] = bv[g]; acc[g][1] = bv[g]; acc[g][2] = bv[g]; acc[g][3] = bv[g];
    }
#pragma unroll
    for (int kc = 0; kc < 8; kc++)
#pragma unroll
      for (int g = 0; g < 4; g++)
        acc[g] = __builtin_amdgcn_mfma_f32_16x16x32_bf16(a[kc], wu[g][kc], acc[g], 0, 0, 0);

    float iv = sigm(acc[0][0]);
    float fv = sigm(acc[1][0]);
    float gv = tanh_(acc[2][0]);
    float ov = sigm(acc[3][0]);
    cc = fv * cc + iv * gv;
    float hv = ov * tanh_(cc);

    xh[nb][quad * 4][128 + tc * 16 + m] = f2bf(hv);
    xh[nb][srow * 4][scol] = f2bf(vx);

    outp[(size_t)s * 256] = hv;

    LDS_BARRIER();
    vx = vnew;
  };

  for (int s = 0; s < NT; s += 2) {
    body(s, vxA);
    body(s + 1, vxB);
  }
}

extern "C" void kernel_launch(void* const* d_in, const int* in_sizes, int n_in,
                              void* d_out, int out_size, void* d_ws, size_t ws_size,
                              hipStream_t stream) {
  const float* x  = (const float*)d_in[0];
  const float* Wf = (const float*)d_in[1];
  const float* Uf = (const float*)d_in[2];
  const float* bf = (const float*)d_in[3];
  const float* Wb = (const float*)d_in[4];
  const float* Ub = (const float*)d_in[5];
  const float* bb = (const float*)d_in[6];
  float* out = (float*)d_out;

  unsigned short* frag = (unsigned short*)d_ws;
  const size_t FRAG_BYTES = 512 * 1024;
  const size_t ZX_BYTES = (size_t)2 * 131072 * 512 * sizeof(float);   // 512 MB

  prep_frags<<<1024, 256, 0, stream>>>(Wf, Uf, Wb, Ub, frag);

  if (ws_size >= FRAG_BYTES + ZX_BYTES) {
    float* zx = (float*)((char*)d_ws + FRAG_BYTES);
    zx_gemm<<<4096, 512, 0, stream>>>(frag, x, bf, bb, zx);
    bilstm_rec_lite<<<128, 512, 0, stream>>>(frag, zx, out);
  } else {
    bilstm_rec_fused<<<128, 512, 0, stream>>>(frag, x, bf, bb, out);
  }
}

// Round 5
// 473.003 us; speedup vs baseline: 1.0455x; 1.0455x over previous
//
#include <hip/hip_runtime.h>

// BiLSTM: B=256, T=512, N=128, H=128. fp32 in/out, bf16 MFMA internally.
//
// 128 blocks = 2 dirs x 64 batch-blocks of 4 rows, rows mapped to MFMA tile
// rows {0,4,8,12} (rows r%4!=0 are permanent zero padding; MFMA C-row r
// depends only on A-row r so padding never contaminates real rows).
// 8 uniform waves; wave = column-slice tc (16 cols x all 4 gates).
//
// Round-5 change vs round-3 (372us): in-register zx software pipeline.
//   Two accumulator sets. At body(s), accCur already holds b + x(t(s))@W
//   (computed at body(s-1)). Serial chain is only: ds_read h -> 4-deep
//   MFMA (U) -> activations -> h write. The 16 x@W MFMAs for step s+1
//   (accNxt) are issued off-chain and fill stall gaps. x is staged one
//   step earlier (body(s) stages x(t(s+2))) so x(t(s+1)) is readable from
//   LDS during body(s). Per-gate C-chain order (b, W kc0-3, U kc0-3) is
//   identical to round 3 -> bit-identical output expected.
//
// ws layout:
//   [0, 512KB): combined WU bf16 B-fragments
//               [dir(2)][gate(4)][kc(8)][tile(8)][lane(64)][8]
//               kc<4 -> W rows kc*32.., kc>=4 -> U rows (kc-4)*32..

typedef short s16x8 __attribute__((ext_vector_type(8)));
typedef float f32x4 __attribute__((ext_vector_type(4)));

#define NT 512
#define LDSROW 264   // bf16 per row: 256 data + 8 pad. 132 dw, 16B-aligned.

// Barrier with LDS-only drain: out-stores and x prefetches stay in flight.
#define LDS_BARRIER() asm volatile("s_waitcnt lgkmcnt(0)\n\ts_barrier" ::: "memory")

__device__ __forceinline__ unsigned short f2bf(float f) {
  unsigned int u = __float_as_uint(f);
  u += 0x7fffu + ((u >> 16) & 1u);   // RNE
  return (unsigned short)(u >> 16);
}
__device__ __forceinline__ float sigm(float x) {
  return __builtin_amdgcn_rcpf(1.f + __expf(-x));
}
__device__ __forceinline__ float tanh_(float x) {
  float xc = fminf(fmaxf(x, -12.f), 12.f);
  return 1.f - 2.f * __builtin_amdgcn_rcpf(1.f + __expf(2.f * xc));
}

// ---------------------------------------------------------------- kernel 0
// Repack [W;U] (fp32 [128][512] each) into bf16 B-fragment order, K=256.
// B-frag (16x16x32): lane holds B[k = (lane>>4)*8 + j][n = lane&15].
__global__ void prep_frags(const float* __restrict__ Wf, const float* __restrict__ Uf,
                           const float* __restrict__ Wb, const float* __restrict__ Ub,
                           unsigned short* __restrict__ frag) {
  int idx = blockIdx.x * 256 + threadIdx.x;          // 0 .. 2^18-1
  int j    = idx & 7;
  int lane = (idx >> 3) & 63;
  int tile = (idx >> 9) & 7;
  int kc   = (idx >> 12) & 7;
  int gate = (idx >> 15) & 3;
  int dir  = (idx >> 17) & 1;
  const float* M = (kc < 4) ? (dir ? Wb : Wf) : (dir ? Ub : Uf);
  int k   = (kc & 3) * 32 + (lane >> 4) * 8 + j;
  int col = gate * 128 + tile * 16 + (lane & 15);
  frag[idx] = f2bf(M[k * 512 + col]);
}

// ---------------------------------------------------------------- kernel 1
__global__ __launch_bounds__(512, 2) void bilstm_rec(
    const unsigned short* __restrict__ frag, const float* __restrict__ x,
    const float* __restrict__ bfw, const float* __restrict__ bbw,
    float* __restrict__ out) {
  __shared__ unsigned short xh[2][16][LDSROW];   // cols 0..127 = x, 128..255 = h

  int bid = blockIdx.x;
  int bblk = bid & 63, dir = bid >> 6;
  int tid = threadIdx.x;
  int tc = tid >> 6, lane = tid & 63, quad = lane >> 4, m = lane & 15;
  bool mrow = ((m & 3) == 0);   // lane holds a real A-row (tile row in {0,4,8,12})

  // WU fragments for (dir, all gates, tile tc): 32 frags -> 128 regs
  s16x8 wu[4][8];   // [gate][kc]: kc 0-3 = W, 4-7 = U
#pragma unroll
  for (int g = 0; g < 4; g++)
#pragma unroll
    for (int kc = 0; kc < 8; kc++)
      wu[g][kc] = *(const s16x8*)(frag +
          ((((size_t)(dir * 4 + g) * 8 + kc) * 8 + tc) * 64 + lane) * 8);

  const float* bias = dir ? bbw : bfw;
  float bv[4];
#pragma unroll
  for (int g = 0; g < 4; g++) bv[g] = bias[g * 128 + tc * 16 + m];

  // x staging ownership: thread -> (real row srow 0..3, col scol 0..127)
  int srow = tid >> 7, scol = tid & 127;
  const float* xsrc = x + ((size_t)(bblk * 4 + srow) * NT) * 128 + scol;

  auto tmap = [&](int s) { int ss = s > NT - 1 ? NT - 1 : s; return dir ? (NT - 1 - ss) : ss; };

  // zero ALL of LDS (padding rows must read 0 forever; h(0) = 0)
  {
    unsigned int* zp = (unsigned int*)&xh[0][0][0];
    for (int i = tid; i < 2 * 16 * (LDSROW / 2); i += 512) zp[i] = 0;
  }

  // 2-deep register prefetch slots (consumed at body(0)/(1) as x(t(2))/x(t(3)))
  float vxA = xsrc[(size_t)tmap(2) * 128];
  float vxB = xsrc[(size_t)tmap(3) * 128];

  // prologue staging: xh[0].x = x(t(1)) (read by body(0) for accNxt),
  //                   xh[1].x = x(t(0)) (read below for the initial accCur).
  float vx1 = xsrc[(size_t)tmap(1) * 128];
  float vx0 = xsrc[(size_t)tmap(0) * 128];
  xh[0][srow * 4][scol] = f2bf(vx1);
  xh[1][srow * 4][scol] = f2bf(vx0);
  __syncthreads();

  // persistent A-frag regs; non-mrow lanes keep zeros (their C rows are padding)
  s16x8 ah[4], ax[4];
#pragma unroll
  for (int kk = 0; kk < 4; kk++) { ah[kk] = (s16x8){0,0,0,0,0,0,0,0}; ax[kk] = (s16x8){0,0,0,0,0,0,0,0}; }

  // initial accCur = b + x(t(0))@W  (reads xh[1].x)
  if (mrow) {
#pragma unroll
    for (int kk = 0; kk < 4; kk++)
      ax[kk] = *(const s16x8*)(&xh[1][m][kk * 32 + quad * 8]);
  }
  __syncthreads();   // all waves done reading xh[1].x before body(0) restages it

  f32x4 accA[4], accB[4];
#pragma unroll
  for (int g = 0; g < 4; g++) {
    accA[g][0] = bv[g]; accA[g][1] = bv[g]; accA[g][2] = bv[g]; accA[g][3] = bv[g];
  }
#pragma unroll
  for (int kk = 0; kk < 4; kk++)
#pragma unroll
    for (int g = 0; g < 4; g++)
      accA[g] = __builtin_amdgcn_mfma_f32_16x16x32_bf16(ax[kk], wu[g][kk], accA[g], 0, 0, 0);

  float cc = 0.f;   // cell state: lane owns (batch row quad, col tc*16+m)
  float* outp = out + ((size_t)(bblk * 4 + quad) * NT) * 256 + dir * 128 + tc * 16 + m;

  auto body = [&](int s, float& vx, f32x4 (&accC)[4], f32x4 (&accN)[4]) {
    int cb = s & 1, nb = cb ^ 1;

    // issue x load for t(s+4) (consumed as stage-write at body(s+2))
    float vnew = xsrc[(size_t)tmap(s + 4) * 128];

    // A-frags, exec-masked to real-row lanes (2-way banks, free):
    // h(s) from xh[cb].h (chain-critical) and x(t(s+1)) from xh[cb].x
    if (mrow) {
#pragma unroll
      for (int kk = 0; kk < 4; kk++)
        ah[kk] = *(const s16x8*)(&xh[cb][m][128 + kk * 32 + quad * 8]);
#pragma unroll
      for (int kk = 0; kk < 4; kk++)
        ax[kk] = *(const s16x8*)(&xh[cb][m][kk * 32 + quad * 8]);
    }

    // finish z(s): continue accC chain with the U half (4-deep per gate)
#pragma unroll
    for (int kk = 0; kk < 4; kk++)
#pragma unroll
      for (int g = 0; g < 4; g++)
        accC[g] = __builtin_amdgcn_mfma_f32_16x16x32_bf16(ah[kk], wu[g][4 + kk], accC[g], 0, 0, 0);

    // start z(s+1): accN = b + x(t(s+1))@W (off the serial chain)
#pragma unroll
    for (int g = 0; g < 4; g++) {
      accN[g][0] = bv[g]; accN[g][1] = bv[g]; accN[g][2] = bv[g]; accN[g][3] = bv[g];
    }
#pragma unroll
    for (int kk = 0; kk < 4; kk++)
#pragma unroll
      for (int g = 0; g < 4; g++)
        accN[g] = __builtin_amdgcn_mfma_f32_16x16x32_bf16(ax[kk], wu[g][kk], accN[g], 0, 0, 0);

    // activations on the single real element: C row quad*4 (reg 0)
    float iv = sigm(accC[0][0]);
    float fv = sigm(accC[1][0]);
    float gv = tanh_(accC[2][0]);
    float ov = sigm(accC[3][0]);
    cc = fv * cc + iv * gv;
    float hv = ov * tanh_(cc);

    // LDS writes (gate the barrier's lgkmcnt drain)
    xh[nb][quad * 4][128 + tc * 16 + m] = f2bf(hv);
    xh[nb][srow * 4][scol] = f2bf(vx);   // stage x(t(s+2))

    // global out store last (stays in flight across the barrier)
    outp[(size_t)s * 256] = hv;

    LDS_BARRIER();
    vx = vnew;   // rotate prefetch slot
  };

  for (int s = 0; s < NT; s += 2) {
    body(s, vxA, accA, accB);
    body(s + 1, vxB, accB, accA);
  }
}

extern "C" void kernel_launch(void* const* d_in, const int* in_sizes, int n_in,
                              void* d_out, int out_size, void* d_ws, size_t ws_size,
                              hipStream_t stream) {
  const float* x  = (const float*)d_in[0];
  const float* Wf = (const float*)d_in[1];
  const float* Uf = (const float*)d_in[2];
  const float* bf = (const float*)d_in[3];
  const float* Wb = (const float*)d_in[4];
  const float* Ub = (const float*)d_in[5];
  const float* bb = (const float*)d_in[6];
  float* out = (float*)d_out;

  unsigned short* frag = (unsigned short*)d_ws;

  prep_frags<<<1024, 256, 0, stream>>>(Wf, Uf, Wb, Ub, frag);
  bilstm_rec<<<128, 512, 0, stream>>>(frag, x, bf, bb, out);
}

// Round 6
// 450.985 us; speedup vs baseline: 1.0966x; 1.0488x over previous
//
#include <hip/hip_runtime.h>

// BiLSTM: B=256, T=512, N=128, H=128. fp32 in/out, bf16 MFMA internally.
//
// 128 blocks = 2 dirs x 64 batch-blocks of 4 rows. h@U uses padded M=16 tile
// (real batch rows at tile rows {0,4,8,12}; padding rows permanent zero).
// 8 uniform waves; wave = column-slice tc (16 cols x all 4 gates).
//
// Round-6 change vs round-5 (357us): dense 4-step-batched x@W.
//   x@W is a parallel GEMM -> compute it for 4 future steps in ONE dense
//   M=16 tile: row = 4*br + ts (br = batch row 0..3, ts = step offset 0..3).
//   Every lane's 4 C-regs are real: accX[g][r] = zx(batch row quad, step
//   4G+r, col tc*16+m) = exactly the acc-init step 4G+r needs. x@W MFMA
//   cost drops 4x: per-step per-wave MFMA 32 -> 20 (16 U + 16/4 dense,
//   one dense kc issued per sub-step to keep steps uniform).
//   Per-gate FP summation order (b -> W kc0..3 -> U kc0..3) unchanged ->
//   bit-identical output expected.
//   x staging: one coalesced float4 per thread per group, ~7 steps of
//   prefetch cover; LDS x buffer [16 rows][128] double-buffered by group.
//
// ws layout:
//   [0, 512KB): combined WU bf16 B-fragments
//               [dir(2)][gate(4)][kc(8)][tile(8)][lane(64)][8]
//               kc<4 -> W rows kc*32.., kc>=4 -> U rows (kc-4)*32..

typedef short s16x8 __attribute__((ext_vector_type(8)));
typedef float f32x4 __attribute__((ext_vector_type(4)));

#define NT 512
#define NG 128          // groups of 4 steps

// Barrier with LDS-only drain: out-stores and x prefetches stay in flight.
#define LDS_BARRIER() asm volatile("s_waitcnt lgkmcnt(0)\n\ts_barrier" ::: "memory")

__device__ __forceinline__ unsigned short f2bf(float f) {
  unsigned int u = __float_as_uint(f);
  u += 0x7fffu + ((u >> 16) & 1u);   // RNE
  return (unsigned short)(u >> 16);
}
__device__ __forceinline__ unsigned int packbf2(float a, float b) {
  return (unsigned int)f2bf(a) | ((unsigned int)f2bf(b) << 16);
}
__device__ __forceinline__ float sigm(float x) {
  return __builtin_amdgcn_rcpf(1.f + __expf(-x));
}
__device__ __forceinline__ float tanh_(float x) {
  float xc = fminf(fmaxf(x, -12.f), 12.f);
  return 1.f - 2.f * __builtin_amdgcn_rcpf(1.f + __expf(2.f * xc));
}

// ---------------------------------------------------------------- kernel 0
// Repack [W;U] (fp32 [128][512] each) into bf16 B-fragment order, K=256.
// B-frag (16x16x32): lane holds B[k = (lane>>4)*8 + j][n = lane&15].
__global__ void prep_frags(const float* __restrict__ Wf, const float* __restrict__ Uf,
                           const float* __restrict__ Wb, const float* __restrict__ Ub,
                           unsigned short* __restrict__ frag) {
  int idx = blockIdx.x * 256 + threadIdx.x;          // 0 .. 2^18-1
  int j    = idx & 7;
  int lane = (idx >> 3) & 63;
  int tile = (idx >> 9) & 7;
  int kc   = (idx >> 12) & 7;
  int gate = (idx >> 15) & 3;
  int dir  = (idx >> 17) & 1;
  const float* M = (kc < 4) ? (dir ? Wb : Wf) : (dir ? Ub : Uf);
  int k   = (kc & 3) * 32 + (lane >> 4) * 8 + j;
  int col = gate * 128 + tile * 16 + (lane & 15);
  frag[idx] = f2bf(M[k * 512 + col]);
}

// ---------------------------------------------------------------- kernel 1
__global__ __launch_bounds__(512, 2) void bilstm_rec(
    const unsigned short* __restrict__ frag, const float* __restrict__ x,
    const float* __restrict__ bfw, const float* __restrict__ bbw,
    float* __restrict__ out) {
  __shared__ unsigned short hbuf[2][16][136];   // h; rows {0,4,8,12} live
  __shared__ unsigned short xbuf[2][16][136];   // x; row 4*br+ts, per-group

  int bid = blockIdx.x;
  int bblk = bid & 63, dir = bid >> 6;
  int tid = threadIdx.x;
  int tc = tid >> 6, lane = tid & 63, quad = lane >> 4, m = lane & 15;
  bool mrow = ((m & 3) == 0);   // lane holds a real h-row

  // WU fragments for (dir, all gates, tile tc): 32 frags
  s16x8 wu[4][8];   // [gate][kc]: kc 0-3 = W, 4-7 = U
#pragma unroll
  for (int g = 0; g < 4; g++)
#pragma unroll
    for (int kc = 0; kc < 8; kc++)
      wu[g][kc] = *(const s16x8*)(frag +
          ((((size_t)(dir * 4 + g) * 8 + kc) * 8 + tc) * 64 + lane) * 8);

  const float* bias = dir ? bbw : bfw;
  float bv[4];
#pragma unroll
  for (int g = 0; g < 4; g++) bv[g] = bias[g * 128 + tc * 16 + m];

  // x staging: thread -> xbuf row (tid>>5) = 4*br+ts, cols (tid&31)*4 (+3)
  int xrow = tid >> 5, xcol = (tid & 31) * 4;
  int sbr = xrow >> 2, sts = xrow & 3;
  const float* xsrc = x + ((size_t)(bblk * 4 + sbr) * NT) * 128 + xcol;

  auto tmap = [&](int s) { int ss = s > NT - 1 ? NT - 1 : s; return dir ? (NT - 1 - ss) : ss; };
  auto ldx4 = [&](int G) -> float4 {           // this thread's x word for group G
    return *(const float4*)(xsrc + (size_t)tmap(4 * G + sts) * 128);
  };
  auto stx = [&](int p, float4 v) {
    uint2 pk; pk.x = packbf2(v.x, v.y); pk.y = packbf2(v.z, v.w);
    *(uint2*)(&xbuf[p][xrow][xcol]) = pk;
  };

  // zero hbuf (padding rows must read 0 forever; h(0) = 0)
  {
    unsigned int* zp = (unsigned int*)&hbuf[0][0][0];
    for (int i = tid; i < 2 * 16 * 68; i += 512) zp[i] = 0;
  }
  // prologue staging: xbuf[0] = x(group 0), xbuf[1] = x(group 1)
  stx(0, ldx4(0));
  stx(1, ldx4(1));
  __syncthreads();

  // prologue: accX0 = b + x(group 0)@W  (dense, all rows real)
  s16x8 ax[4];
#pragma unroll
  for (int kk = 0; kk < 4; kk++)
    ax[kk] = *(const s16x8*)(&xbuf[0][m][kk * 32 + quad * 8]);
  f32x4 accX0[4], accX1[4];
#pragma unroll
  for (int g = 0; g < 4; g++) {
    accX0[g][0] = bv[g]; accX0[g][1] = bv[g]; accX0[g][2] = bv[g]; accX0[g][3] = bv[g];
  }
#pragma unroll
  for (int kk = 0; kk < 4; kk++)
#pragma unroll
    for (int g = 0; g < 4; g++)
      accX0[g] = __builtin_amdgcn_mfma_f32_16x16x32_bf16(ax[kk], wu[g][kk], accX0[g], 0, 0, 0);

  float4 vslot = ldx4(2);   // register prefetch slot (x for group 2)

  s16x8 ah[4];
#pragma unroll
  for (int kk = 0; kk < 4; kk++) ah[kk] = (s16x8){0, 0, 0, 0, 0, 0, 0, 0};

  float cc = 0.f;   // cell state: lane owns (batch row quad, col tc*16+m)
  float* outp = out + ((size_t)(bblk * 4 + quad) * NT) * 256 + dir * 128 + tc * 16 + m;

  // one recurrent sub-step; sub is a literal -> all indexing static
  auto substep = [&](int s, int sub, int p, f32x4 (&accXc)[4], f32x4 (&accXn)[4]) {
    int cb = s & 1, nb = cb ^ 1;

    // h(s) A-frags, exec-masked to real-row lanes (2-way banks, free)
    if (mrow) {
#pragma unroll
      for (int kk = 0; kk < 4; kk++)
        ah[kk] = *(const s16x8*)(&hbuf[cb][m][kk * 32 + quad * 8]);
    }
    if (sub == 0) {
      // dense x A-frags for group G+1 (read after ah: in-order LDS returns
      // let the U-chain start before these complete)
#pragma unroll
      for (int kk = 0; kk < 4; kk++)
        ax[kk] = *(const s16x8*)(&xbuf[p ^ 1][m][kk * 32 + quad * 8]);
#pragma unroll
      for (int g = 0; g < 4; g++) {
        accXn[g][0] = bv[g]; accXn[g][1] = bv[g]; accXn[g][2] = bv[g]; accXn[g][3] = bv[g];
      }
    }

    // serial chain: z(s) = accXc[.][sub] + h(s)@U (4-deep per gate)
    f32x4 acc[4];
#pragma unroll
    for (int g = 0; g < 4; g++) {
      float z = accXc[g][sub];
      acc[g][0] = z; acc[g][1] = z; acc[g][2] = z; acc[g][3] = z;
    }
#pragma unroll
    for (int kk = 0; kk < 4; kk++)
#pragma unroll
      for (int g = 0; g < 4; g++)
        acc[g] = __builtin_amdgcn_mfma_f32_16x16x32_bf16(ah[kk], wu[g][4 + kk], acc[g], 0, 0, 0);

    // off-chain: one dense kc for next group's accX
#pragma unroll
    for (int g = 0; g < 4; g++)
      accXn[g] = __builtin_amdgcn_mfma_f32_16x16x32_bf16(ax[sub], wu[g][sub], accXn[g], 0, 0, 0);

    // activations on the single real element: C row quad*4 (reg 0)
    float iv = sigm(acc[0][0]);
    float fv = sigm(acc[1][0]);
    float gv = tanh_(acc[2][0]);
    float ov = sigm(acc[3][0]);
    cc = fv * cc + iv * gv;
    float hv = ov * tanh_(cc);

    hbuf[nb][quad * 4][tc * 16 + m] = f2bf(hv);   // gates the lgkm drain
    outp[(size_t)s * 256] = hv;                   // stays in flight past barrier
  };

  auto group = [&](int G, int p, f32x4 (&accXc)[4], f32x4 (&accXn)[4]) {
    int s0 = 4 * G;
    float4 vnew = ldx4(G + 3);    // issue early: consumed at (G+1).sub3
    substep(s0 + 0, 0, p, accXc, accXn);
    LDS_BARRIER();
    substep(s0 + 1, 1, p, accXc, accXn);
    LDS_BARRIER();
    substep(s0 + 2, 2, p, accXc, accXn);
    LDS_BARRIER();
    substep(s0 + 3, 3, p, accXc, accXn);
    stx(p, vslot);                // stage x(group G+2) into xbuf[p]
    LDS_BARRIER();
    vslot = vnew;
  };

  for (int G = 0; G < NG; G += 2) {
    group(G, 0, accX0, accX1);
    group(G + 1, 1, accX1, accX0);
  }
}

extern "C" void kernel_launch(void* const* d_in, const int* in_sizes, int n_in,
                              void* d_out, int out_size, void* d_ws, size_t ws_size,
                              hipStream_t stream) {
  const float* x  = (const float*)d_in[0];
  const float* Wf = (const float*)d_in[1];
  const float* Uf = (const float*)d_in[2];
  const float* bf = (const float*)d_in[3];
  const float* Wb = (const float*)d_in[4];
  const float* Ub = (const float*)d_in[5];
  const float* bb = (const float*)d_in[6];
  float* out = (float*)d_out;

  unsigned short* frag = (unsigned short*)d_ws;

  prep_frags<<<1024, 256, 0, stream>>>(Wf, Uf, Wb, Ub, frag);
  bilstm_rec<<<128, 512, 0, stream>>>(frag, x, bf, bb, out);
}

// Round 8
// 442.156 us; speedup vs baseline: 1.1185x; 1.0200x over previous
//
#include <hip/hip_runtime.h>

// BiLSTM: B=256, T=512, N=128, H=128. fp32 in/out, bf16 MFMA internally.
//
// 128 blocks = 2 dirs x 64 batch-blocks of 4 rows. h@U uses padded M=16 tile
// (real batch rows at tile rows {0,4,8,12}; padding rows permanent zero).
// 8 uniform waves; wave = column-slice tc (16 cols x all 4 gates).
// Dense 4-step-batched x@W (round 6): one dense M=16 tile per 4 steps,
// row = 4*br + ts; accX[g][r] = zx for (row quad, step 4G+r, col tc*16+m).
//
// Round-8 = round-7 resubmitted (container infra failure, kernel never ran):
//   * Wave anti-phasing: waves tc>=4 get s_setprio(1) permanently. The two
//     waves sharing a SIMD (w, w+4 under round-robin mapping) were
//     phase-locked: both issue 20 MFMAs (pipe-serialized, ~776cy/SIMD),
//     then both do ~340cy of activation VALU -> step = sum, not max
//     (MfmaUtil+VALUBusy summed to ~89% of step). Priority makes the hi
//     wave drain its MFMAs first and run its VALU under the lo wave's
//     MFMAs: step ~= 776 + 340 instead of 776 + 686.
//   * Persistent accS with elem-0-only init (4 movs instead of 16/step):
//     elems 1-3 belong to zero-padding C rows, receive zero contributions
//     from the U chain forever, so they may hold stale values.
//   Numerics of the real element are unchanged -> bit-identical output.
//
// ws layout:
//   [0, 512KB): combined WU bf16 B-fragments
//               [dir(2)][gate(4)][kc(8)][tile(8)][lane(64)][8]
//               kc<4 -> W rows kc*32.., kc>=4 -> U rows (kc-4)*32..

typedef short s16x8 __attribute__((ext_vector_type(8)));
typedef float f32x4 __attribute__((ext_vector_type(4)));

#define NT 512
#define NG 128          // groups of 4 steps

// Barrier with LDS-only drain: out-stores and x prefetches stay in flight.
#define LDS_BARRIER() asm volatile("s_waitcnt lgkmcnt(0)\n\ts_barrier" ::: "memory")

__device__ __forceinline__ unsigned short f2bf(float f) {
  unsigned int u = __float_as_uint(f);
  u += 0x7fffu + ((u >> 16) & 1u);   // RNE
  return (unsigned short)(u >> 16);
}
__device__ __forceinline__ unsigned int packbf2(float a, float b) {
  return (unsigned int)f2bf(a) | ((unsigned int)f2bf(b) << 16);
}
__device__ __forceinline__ float sigm(float x) {
  return __builtin_amdgcn_rcpf(1.f + __expf(-x));
}
__device__ __forceinline__ float tanh_(float x) {
  float xc = fminf(fmaxf(x, -12.f), 12.f);
  return 1.f - 2.f * __builtin_amdgcn_rcpf(1.f + __expf(2.f * xc));
}

// ---------------------------------------------------------------- kernel 0
// Repack [W;U] (fp32 [128][512] each) into bf16 B-fragment order, K=256.
// B-frag (16x16x32): lane holds B[k = (lane>>4)*8 + j][n = lane&15].
__global__ void prep_frags(const float* __restrict__ Wf, const float* __restrict__ Uf,
                           const float* __restrict__ Wb, const float* __restrict__ Ub,
                           unsigned short* __restrict__ frag) {
  int idx = blockIdx.x * 256 + threadIdx.x;          // 0 .. 2^18-1
  int j    = idx & 7;
  int lane = (idx >> 3) & 63;
  int tile = (idx >> 9) & 7;
  int kc   = (idx >> 12) & 7;
  int gate = (idx >> 15) & 3;
  int dir  = (idx >> 17) & 1;
  const float* M = (kc < 4) ? (dir ? Wb : Wf) : (dir ? Ub : Uf);
  int k   = (kc & 3) * 32 + (lane >> 4) * 8 + j;
  int col = gate * 128 + tile * 16 + (lane & 15);
  frag[idx] = f2bf(M[k * 512 + col]);
}

// ---------------------------------------------------------------- kernel 1
__global__ __launch_bounds__(512, 2) void bilstm_rec(
    const unsigned short* __restrict__ frag, const float* __restrict__ x,
    const float* __restrict__ bfw, const float* __restrict__ bbw,
    float* __restrict__ out) {
  __shared__ unsigned short hbuf[2][16][136];   // h; rows {0,4,8,12} live
  __shared__ unsigned short xbuf[2][16][136];   // x; row 4*br+ts, per-group

  int bid = blockIdx.x;
  int bblk = bid & 63, dir = bid >> 6;
  int tid = threadIdx.x;
  int tc = tid >> 6, lane = tid & 63, quad = lane >> 4, m = lane & 15;
  bool mrow = ((m & 3) == 0);   // lane holds a real h-row

  // Anti-phase the two waves sharing a SIMD (round-robin: w and w+4).
  if (tc >= 4) __builtin_amdgcn_s_setprio(1);

  // WU fragments for (dir, all gates, tile tc): 32 frags
  s16x8 wu[4][8];   // [gate][kc]: kc 0-3 = W, 4-7 = U
#pragma unroll
  for (int g = 0; g < 4; g++)
#pragma unroll
    for (int kc = 0; kc < 8; kc++)
      wu[g][kc] = *(const s16x8*)(frag +
          ((((size_t)(dir * 4 + g) * 8 + kc) * 8 + tc) * 64 + lane) * 8);

  const float* bias = dir ? bbw : bfw;
  float bv[4];
#pragma unroll
  for (int g = 0; g < 4; g++) bv[g] = bias[g * 128 + tc * 16 + m];

  // x staging: thread -> xbuf row (tid>>5) = 4*br+ts, cols (tid&31)*4 (+3)
  int xrow = tid >> 5, xcol = (tid & 31) * 4;
  int sbr = xrow >> 2, sts = xrow & 3;
  const float* xsrc = x + ((size_t)(bblk * 4 + sbr) * NT) * 128 + xcol;

  auto tmap = [&](int s) { int ss = s > NT - 1 ? NT - 1 : s; return dir ? (NT - 1 - ss) : ss; };
  auto ldx4 = [&](int G) -> float4 {           // this thread's x word for group G
    return *(const float4*)(xsrc + (size_t)tmap(4 * G + sts) * 128);
  };
  auto stx = [&](int p, float4 v) {
    uint2 pk; pk.x = packbf2(v.x, v.y); pk.y = packbf2(v.z, v.w);
    *(uint2*)(&xbuf[p][xrow][xcol]) = pk;
  };

  // zero hbuf (padding rows must read 0 forever; h(0) = 0)
  {
    unsigned int* zp = (unsigned int*)&hbuf[0][0][0];
    for (int i = tid; i < 2 * 16 * 68; i += 512) zp[i] = 0;
  }
  // prologue staging: xbuf[0] = x(group 0), xbuf[1] = x(group 1)
  stx(0, ldx4(0));
  stx(1, ldx4(1));
  __syncthreads();

  // prologue: accX0 = b + x(group 0)@W  (dense, all rows real)
  s16x8 ax[4];
#pragma unroll
  for (int kk = 0; kk < 4; kk++)
    ax[kk] = *(const s16x8*)(&xbuf[0][m][kk * 32 + quad * 8]);
  f32x4 accX0[4], accX1[4];
#pragma unroll
  for (int g = 0; g < 4; g++) {
    accX0[g][0] = bv[g]; accX0[g][1] = bv[g]; accX0[g][2] = bv[g]; accX0[g][3] = bv[g];
  }
#pragma unroll
  for (int kk = 0; kk < 4; kk++)
#pragma unroll
    for (int g = 0; g < 4; g++)
      accX0[g] = __builtin_amdgcn_mfma_f32_16x16x32_bf16(ax[kk], wu[g][kk], accX0[g], 0, 0, 0);

  float4 vslot = ldx4(2);   // register prefetch slot (x for group 2)

  s16x8 ah[4];
#pragma unroll
  for (int kk = 0; kk < 4; kk++) ah[kk] = (s16x8){0, 0, 0, 0, 0, 0, 0, 0};

  // persistent serial-chain accumulator: only elem 0 is ever real; elems
  // 1..3 (padding C rows) receive zero contributions forever -> init once.
  f32x4 accS[4];
#pragma unroll
  for (int g = 0; g < 4; g++) {
    accS[g][0] = 0.f; accS[g][1] = 0.f; accS[g][2] = 0.f; accS[g][3] = 0.f;
  }

  float cc = 0.f;   // cell state: lane owns (batch row quad, col tc*16+m)
  float* outp = out + ((size_t)(bblk * 4 + quad) * NT) * 256 + dir * 128 + tc * 16 + m;

  // one recurrent sub-step; sub is a literal -> all indexing static
  auto substep = [&](int s, int sub, int p, f32x4 (&accXc)[4], f32x4 (&accXn)[4]) {
    int cb = s & 1, nb = cb ^ 1;

    // h(s) A-frags, exec-masked to real-row lanes (2-way banks, free)
    if (mrow) {
#pragma unroll
      for (int kk = 0; kk < 4; kk++)
        ah[kk] = *(const s16x8*)(&hbuf[cb][m][kk * 32 + quad * 8]);
    }
    if (sub == 0) {
      // dense x A-frags for group G+1 (read after ah: in-order LDS returns
      // let the U-chain start before these complete)
#pragma unroll
      for (int kk = 0; kk < 4; kk++)
        ax[kk] = *(const s16x8*)(&xbuf[p ^ 1][m][kk * 32 + quad * 8]);
#pragma unroll
      for (int g = 0; g < 4; g++) {
        accXn[g][0] = bv[g]; accXn[g][1] = bv[g]; accXn[g][2] = bv[g]; accXn[g][3] = bv[g];
      }
    }

    // serial chain: z(s) = accXc[.][sub] + h(s)@U (4-deep per gate)
#pragma unroll
    for (int g = 0; g < 4; g++)
      accS[g][0] = accXc[g][sub];
#pragma unroll
    for (int kk = 0; kk < 4; kk++)
#pragma unroll
      for (int g = 0; g < 4; g++)
        accS[g] = __builtin_amdgcn_mfma_f32_16x16x32_bf16(ah[kk], wu[g][4 + kk], accS[g], 0, 0, 0);

    // off-chain: one dense kc for next group's accX
#pragma unroll
    for (int g = 0; g < 4; g++)
      accXn[g] = __builtin_amdgcn_mfma_f32_16x16x32_bf16(ax[sub], wu[g][sub], accXn[g], 0, 0, 0);

    // activations on the single real element: C row quad*4 (reg 0)
    float iv = sigm(accS[0][0]);
    float fv = sigm(accS[1][0]);
    float gv = tanh_(accS[2][0]);
    float ov = sigm(accS[3][0]);
    cc = fv * cc + iv * gv;
    float hv = ov * tanh_(cc);

    hbuf[nb][quad * 4][tc * 16 + m] = f2bf(hv);   // gates the lgkm drain
    outp[(size_t)s * 256] = hv;                   // stays in flight past barrier
  };

  auto group = [&](int G, int p, f32x4 (&accXc)[4], f32x4 (&accXn)[4]) {
    int s0 = 4 * G;
    float4 vnew = ldx4(G + 3);    // issue early: consumed at (G+1).sub3
    substep(s0 + 0, 0, p, accXc, accXn);
    LDS_BARRIER();
    substep(s0 + 1, 1, p, accXc, accXn);
    LDS_BARRIER();
    substep(s0 + 2, 2, p, accXc, accXn);
    LDS_BARRIER();
    substep(s0 + 3, 3, p, accXc, accXn);
    stx(p, vslot);                // stage x(group G+2) into xbuf[p]
    LDS_BARRIER();
    vslot = vnew;
  };

  for (int G = 0; G < NG; G += 2) {
    group(G, 0, accX0, accX1);
    group(G + 1, 1, accX1, accX0);
  }
}

extern "C" void kernel_launch(void* const* d_in, const int* in_sizes, int n_in,
                              void* d_out, int out_size, void* d_ws, size_t ws_size,
                              hipStream_t stream) {
  const float* x  = (const float*)d_in[0];
  const float* Wf = (const float*)d_in[1];
  const float* Uf = (const float*)d_in[2];
  const float* bf = (const float*)d_in[3];
  const float* Wb = (const float*)d_in[4];
  const float* Ub = (const float*)d_in[5];
  const float* bb = (const float*)d_in[6];
  float* out = (float*)d_out;

  unsigned short* frag = (unsigned short*)d_ws;

  prep_frags<<<1024, 256, 0, stream>>>(Wf, Uf, Wb, Ub, frag);
  bilstm_rec<<<128, 512, 0, stream>>>(frag, x, bf, bb, out);
}